// Round 7
// baseline (745.597 us; speedup 1.0000x reference)
//
#include <hip/hip_runtime.h>

// DeeperGCN round 7.
// Round-6 counters: conv_mlp 68us, 3.6M LDS bank-conflict cycles (ws reads at
// j0=tx*8 -> 4-way), occupancy 22% (51.7KB LDS). Fixes: (1) W1 streamed from
// global/L1 like W2 (phase B proved this works) -> no staging, no conflicts;
// (2) split col mapping j0 in {tx*4, 64+tx*4} -> coalesced 256B weight reads;
// (3) LDS = single 64x132 buffer (X in-place then H') = 33.8KB -> 4 blocks/CU.
// head: LDS only for X/Y tile (17.4KB), weights from global.

#define NN 100000
#define NE 800000
#define CH 64
#define NC (NN * CH)
#define H1 128
#define NT 1563            // ceil(NN / 64) node tiles
#define SB 98              // scan blocks
#define EPS_MSG 1e-7f
#define EPS_LN 1e-5f

// ---------------- counting sort: histogram ----------------
__global__ __launch_bounds__(256) void hist_kernel(const int* __restrict__ ei,
                                                   int* __restrict__ cursor) {
    int e = blockIdx.x * 256 + threadIdx.x;
    if (e < NE) atomicAdd(&cursor[ei[NE + e]], 1);
}

// ---------------- hierarchical scan ----------------
__global__ __launch_bounds__(256) void scan1_kernel(const int* __restrict__ cursor,
                                                    int* __restrict__ part) {
    __shared__ int sp[4];
    const int t = threadIdx.x;
    const int i0 = blockIdx.x * 1024 + t * 4;
    int s = 0;
    #pragma unroll
    for (int j = 0; j < 4; ++j) { int i = i0 + j; if (i < NN) s += cursor[i]; }
    #pragma unroll
    for (int o = 32; o; o >>= 1) s += __shfl_xor(s, o);
    if ((t & 63) == 0) sp[t >> 6] = s;
    __syncthreads();
    if (t == 0) part[blockIdx.x] = sp[0] + sp[1] + sp[2] + sp[3];
}

__global__ __launch_bounds__(128) void scan2_kernel(int* __restrict__ part,
                                                    int* __restrict__ off) {
    __shared__ int sc[128];
    const int t = threadIdx.x;
    int v = (t < SB) ? part[t] : 0;
    sc[t] = v;
    __syncthreads();
    for (int o = 1; o < 128; o <<= 1) {
        int u = (t >= o) ? sc[t - o] : 0;
        __syncthreads();
        sc[t] += u;
        __syncthreads();
    }
    if (t < SB) part[t] = sc[t] - v;
    if (t == 0) off[NN] = NE;
}

__global__ __launch_bounds__(256) void scan3_kernel(const int* __restrict__ part,
                                                    int* __restrict__ cursor,
                                                    int* __restrict__ off) {
    __shared__ int sc[256];
    const int t = threadIdx.x;
    const int i0 = blockIdx.x * 1024 + t * 4;
    int deg[4];
    int s = 0;
    #pragma unroll
    for (int j = 0; j < 4; ++j) { int i = i0 + j; deg[j] = (i < NN) ? cursor[i] : 0; s += deg[j]; }
    sc[t] = s;
    __syncthreads();
    for (int o = 1; o < 256; o <<= 1) {
        int u = (t >= o) ? sc[t - o] : 0;
        __syncthreads();
        sc[t] += u;
        __syncthreads();
    }
    int run = part[blockIdx.x] + sc[t] - s;
    #pragma unroll
    for (int j = 0; j < 4; ++j) {
        int i = i0 + j;
        if (i < NN) { off[i] = run; cursor[i] = run; run += deg[j]; }
    }
}

// ---------------- scatter src ids grouped by dst ----------------
__global__ __launch_bounds__(256) void scatter_kernel(const int* __restrict__ ei,
                                                      int* __restrict__ cursor,
                                                      int* __restrict__ esrc) {
    int e = blockIdx.x * 256 + threadIdx.x;
    if (e >= NE) return;
    int dst = ei[NE + e];
    int pos = atomicAdd(&cursor[dst], 1);
    esrc[pos] = ei[e];
}

// ---------------- aggregation: wave per node, channel per lane ----------------
template <int MODE>
__global__ __launch_bounds__(256) void agg_kernel(
    const float* __restrict__ xin, const int* __restrict__ off,
    const int* __restrict__ esrc, const double* __restrict__ ds_in,
    const float* __restrict__ gw, const float* __restrict__ gb,
    float* __restrict__ hbuf)
{
    const int lane = threadIdx.x & 63;
    const int n = __builtin_amdgcn_readfirstlane((blockIdx.x * 256 + threadIdx.x) >> 6);
    if (n >= NN) return;
    float A = 1.f, B = 0.f;
    if (MODE) {
        double S = ds_in[0], Q = ds_in[1];
        double mud = S / (double)NC;
        float var = (float)(Q / (double)NC - mud * mud);
        float scale = 1.f / (sqrtf(fmaxf(var, 0.f)) + EPS_LN);
        A = scale * gw[lane];
        B = fmaf(-(float)mud, A, gb[lane]);
    }
    const size_t base = (size_t)n * CH + lane;
    const float xb = xin[base];
    const int p0 = off[n], p1 = off[n + 1];
    float den = 0.f, num = 0.f;
    for (int q = p0; q < p1; q += 8) {
        int m = p1 - q; if (m > 8) m = 8;
        float v[8];
        #pragma unroll
        for (int i = 0; i < 8; ++i)
            if (i < m) v[i] = xin[(size_t)esrc[q + i] * CH + lane];
        #pragma unroll
        for (int i = 0; i < 8; ++i)
            if (i < m) {
                float mm = MODE ? fmaxf(fmaf(v[i], A, B), 0.f) + EPS_MSG
                                : fmaxf(v[i], 0.f) + EPS_MSG;
                float e = __expf(mm);
                den += e;
                num = fmaf(mm, e, num);
            }
    }
    float agg = den > 0.f ? num / den : 0.f;
    float xl = MODE ? fmaxf(fmaf(xb, A, B), 0.f) : xb;
    hbuf[base] = agg + xl;
}

// ---------------- fused conv MLP: block-tiled double GEMM ----------------
// 64-node tile/block. Phase A: H = X@W1+b1 (acc[4][8], W1 from global/L1,
// cols {tx*4, 64+tx*4}); row-LN+relu via shfl; H' -> LDS; Phase B: O = H'@W2+b2.
template <int MODE>
__global__ __launch_bounds__(256) void conv_mlp_kernel(
    const float* __restrict__ hbuf, const float* __restrict__ xres,
    const float* __restrict__ W1, const float* __restrict__ b1,
    const float* __restrict__ lnw, const float* __restrict__ lnb,
    const float* __restrict__ W2, const float* __restrict__ b2,
    float* __restrict__ out, double* __restrict__ ds_out)
{
    __shared__ float smem[64 * 132];    // 33.8 KB: X [64][68] (phase A) -> H' [64][132] (phase B)
    __shared__ float sstat[8];
    float* xs = smem;
    float* hs = smem;
    const int t = threadIdx.x;
    const int base = blockIdx.x * 64;
    const int nvalid = (NN - base < 64) ? (NN - base) : 64;

    // stage X tile (row-clamped)
    #pragma unroll
    for (int j = 0; j < 4; ++j) {
        const int idx = j * 256 + t;            // 1024 float4s, 16 per row
        const int r = idx >> 4;
        const int c = (idx & 15) * 4;
        const int rn = (r < nvalid) ? r : (nvalid - 1);
        *reinterpret_cast<float4*>(xs + r * 68 + c) =
            *reinterpret_cast<const float4*>(hbuf + (size_t)(base + rn) * CH + c);
    }
    __syncthreads();

    const int tx = t & 15, ty = t >> 4;
    const int r0 = ty * 4;              // 4 node-rows
    const int j0 = tx * 4;              // cols j0..j0+3 and 64+j0..64+j0+3

    // phase A: acc[i][0..3] = cols j0 block, acc[i][4..7] = cols 64+j0 block
    float acc[4][8];
    #pragma unroll
    for (int i = 0; i < 4; ++i)
        #pragma unroll
        for (int j = 0; j < 8; ++j) acc[i][j] = 0.f;
    for (int k = 0; k < 64; k += 4) {
        float av[4][4];
        #pragma unroll
        for (int i = 0; i < 4; ++i) {
            const float4 v = *reinterpret_cast<const float4*>(xs + (r0 + i) * 68 + k);
            av[i][0] = v.x; av[i][1] = v.y; av[i][2] = v.z; av[i][3] = v.w;
        }
        #pragma unroll
        for (int kk = 0; kk < 4; ++kk) {
            const float4 w0 = *reinterpret_cast<const float4*>(W1 + (k + kk) * H1 + j0);
            const float4 w1v = *reinterpret_cast<const float4*>(W1 + (k + kk) * H1 + 64 + j0);
            const float bv[8] = {w0.x, w0.y, w0.z, w0.w, w1v.x, w1v.y, w1v.z, w1v.w};
            #pragma unroll
            for (int i = 0; i < 4; ++i)
                #pragma unroll
                for (int j = 0; j < 8; ++j)
                    acc[i][j] = fmaf(av[i][kk], bv[j], acc[i][j]);
        }
    }

    // + b1, per-row LN stats (row spread over 16 tx lanes)
    {
        const float4 bb0 = *reinterpret_cast<const float4*>(b1 + j0);
        const float4 bb1 = *reinterpret_cast<const float4*>(b1 + 64 + j0);
        const float bj[8] = {bb0.x, bb0.y, bb0.z, bb0.w, bb1.x, bb1.y, bb1.z, bb1.w};
        #pragma unroll
        for (int i = 0; i < 4; ++i)
            #pragma unroll
            for (int j = 0; j < 8; ++j) acc[i][j] += bj[j];
    }
    float rs[4], rq[4];
    #pragma unroll
    for (int i = 0; i < 4; ++i) {
        float s = 0.f, q = 0.f;
        #pragma unroll
        for (int j = 0; j < 8; ++j) { s += acc[i][j]; q = fmaf(acc[i][j], acc[i][j], q); }
        rs[i] = s; rq[i] = q;
    }
    #pragma unroll
    for (int o = 1; o <= 8; o <<= 1) {
        #pragma unroll
        for (int i = 0; i < 4; ++i) {
            rs[i] += __shfl_xor(rs[i], o);
            rq[i] += __shfl_xor(rq[i], o);
        }
    }
    // normalize + affine + relu
    {
        const float4 g0 = *reinterpret_cast<const float4*>(lnw + j0);
        const float4 g1 = *reinterpret_cast<const float4*>(lnw + 64 + j0);
        const float4 c0 = *reinterpret_cast<const float4*>(lnb + j0);
        const float4 c1 = *reinterpret_cast<const float4*>(lnb + 64 + j0);
        const float gj[8] = {g0.x, g0.y, g0.z, g0.w, g1.x, g1.y, g1.z, g1.w};
        const float cj[8] = {c0.x, c0.y, c0.z, c0.w, c1.x, c1.y, c1.z, c1.w};
        #pragma unroll
        for (int i = 0; i < 4; ++i) {
            const float mu = rs[i] * (1.f / 128.f);
            const float var = rq[i] * (1.f / 128.f) - mu * mu;
            const float rstd = 1.f / sqrtf(var + EPS_LN);
            #pragma unroll
            for (int j = 0; j < 8; ++j)
                acc[i][j] = fmaxf(fmaf((acc[i][j] - mu) * rstd, gj[j], cj[j]), 0.f);
        }
    }
    __syncthreads();                    // everyone done reading xs
    #pragma unroll
    for (int i = 0; i < 4; ++i) {
        float4 v0, v1;
        v0.x = acc[i][0]; v0.y = acc[i][1]; v0.z = acc[i][2]; v0.w = acc[i][3];
        v1.x = acc[i][4]; v1.y = acc[i][5]; v1.z = acc[i][6]; v1.w = acc[i][7];
        *reinterpret_cast<float4*>(hs + (r0 + i) * 132 + j0) = v0;
        *reinterpret_cast<float4*>(hs + (r0 + i) * 132 + 64 + j0) = v1;
    }
    __syncthreads();

    // phase B: O = H' @ W2 + b2 ; acc2[4][4]; W2 rows from global (L1-resident)
    const int j2 = tx * 4;
    float acc2[4][4];
    #pragma unroll
    for (int i = 0; i < 4; ++i)
        #pragma unroll
        for (int j = 0; j < 4; ++j) acc2[i][j] = 0.f;
    for (int k = 0; k < 128; k += 4) {
        float av[4][4];
        #pragma unroll
        for (int i = 0; i < 4; ++i) {
            const float4 v = *reinterpret_cast<const float4*>(hs + (r0 + i) * 132 + k);
            av[i][0] = v.x; av[i][1] = v.y; av[i][2] = v.z; av[i][3] = v.w;
        }
        #pragma unroll
        for (int kk = 0; kk < 4; ++kk) {
            const float4 w = *reinterpret_cast<const float4*>(W2 + (k + kk) * CH + j2);
            const float wv[4] = {w.x, w.y, w.z, w.w};
            #pragma unroll
            for (int i = 0; i < 4; ++i)
                #pragma unroll
                for (int j = 0; j < 4; ++j)
                    acc2[i][j] = fmaf(av[i][kk], wv[j], acc2[i][j]);
        }
    }

    // epilogue: +b2, +residual, store, stats
    const float4 b2v = *reinterpret_cast<const float4*>(b2 + j2);
    float as = 0.f, aq = 0.f;
    #pragma unroll
    for (int i = 0; i < 4; ++i) {
        const int r = r0 + i;
        if (r < nvalid) {
            float v0 = acc2[i][0] + b2v.x;
            float v1 = acc2[i][1] + b2v.y;
            float v2 = acc2[i][2] + b2v.z;
            float v3 = acc2[i][3] + b2v.w;
            const size_t gi = (size_t)(base + r) * CH + j2;
            if (MODE) {
                const float4 xr = *reinterpret_cast<const float4*>(xres + gi);
                v0 += xr.x; v1 += xr.y; v2 += xr.z; v3 += xr.w;
            }
            float4 st; st.x = v0; st.y = v1; st.z = v2; st.w = v3;
            *reinterpret_cast<float4*>(out + gi) = st;
            as += (v0 + v1) + (v2 + v3);
            aq += fmaf(v0, v0, v1 * v1) + fmaf(v2, v2, v3 * v3);
        }
    }
    #pragma unroll
    for (int o = 32; o; o >>= 1) { as += __shfl_xor(as, o); aq += __shfl_xor(aq, o); }
    const int lane = t & 63, wv2 = t >> 6;
    if (lane == 0) { sstat[wv2] = as; sstat[4 + wv2] = aq; }
    __syncthreads();
    if (t == 0) {
        unsafeAtomicAdd(ds_out + 0, (double)(sstat[0] + sstat[1] + sstat[2] + sstat[3]));
        unsafeAtomicAdd(ds_out + 1, (double)(sstat[4] + sstat[5] + sstat[6] + sstat[7]));
    }
}

// ---------------- layer-1 graph-LN apply (+relu) with output stats ----------------
__global__ __launch_bounds__(256) void ln_apply_kernel(
    const float* __restrict__ in, const float* __restrict__ w,
    const float* __restrict__ b, const double* __restrict__ ds_in,
    float* __restrict__ out, double* __restrict__ ds_out)
{
    __shared__ float ps[4], pq[4];
    double S = ds_in[0], Q = ds_in[1];
    double mud = S / (double)NC;
    float mu = (float)mud;
    float var = (float)(Q / (double)NC - mud * mud);
    float scale = 1.f / (sqrtf(fmaxf(var, 0.f)) + EPS_LN);
    float s = 0.f, q = 0.f;
    int idx = blockIdx.x * 256 + threadIdx.x;
    int stride = gridDim.x * 256;
    for (int i = idx; i < NC / 4; i += stride) {
        int c = (i & 15) << 2;
        float4 v = reinterpret_cast<const float4*>(in)[i];
        float4 wv = *reinterpret_cast<const float4*>(w + c);
        float4 bv = *reinterpret_cast<const float4*>(b + c);
        float4 o;
        o.x = fmaxf(fmaf((v.x - mu) * scale, wv.x, bv.x), 0.f);
        o.y = fmaxf(fmaf((v.y - mu) * scale, wv.y, bv.y), 0.f);
        o.z = fmaxf(fmaf((v.z - mu) * scale, wv.z, bv.z), 0.f);
        o.w = fmaxf(fmaf((v.w - mu) * scale, wv.w, bv.w), 0.f);
        reinterpret_cast<float4*>(out)[i] = o;
        s += (o.x + o.y) + (o.z + o.w);
        q += fmaf(o.x, o.x, o.y * o.y) + fmaf(o.z, o.z, o.w * o.w);
    }
    int lane = threadIdx.x & 63, wv2 = threadIdx.x >> 6;
    #pragma unroll
    for (int o = 32; o; o >>= 1) { s += __shfl_xor(s, o); q += __shfl_xor(q, o); }
    if (lane == 0) { ps[wv2] = s; pq[wv2] = q; }
    __syncthreads();
    if (threadIdx.x == 0) {
        unsafeAtomicAdd(ds_out + 0, (double)((ps[0] + ps[1]) + (ps[2] + ps[3])));
        unsafeAtomicAdd(ds_out + 1, (double)((pq[0] + pq[1]) + (pq[2] + pq[3])));
    }
}

// ---------------- head: block-tiled GEMMs, X/Y tile in LDS, weights global ----------------
__global__ __launch_bounds__(256) void head_kernel(
    const float* __restrict__ xc,
    const float* __restrict__ W1, const float* __restrict__ b1,
    const float* __restrict__ W2, const float* __restrict__ b2,
    const float* __restrict__ W3, const float* __restrict__ b3,
    float* __restrict__ out)
{
    __shared__ float xs[64 * 68];       // 17.4 KB
    const int t = threadIdx.x;
    const int base = blockIdx.x * 64;
    const int nvalid = (NN - base < 64) ? (NN - base) : 64;
    const int tx = t & 15, ty = t >> 4;
    const int r0 = ty * 4, j2 = tx * 4;

    #pragma unroll
    for (int j = 0; j < 4; ++j) {
        const int idx = j * 256 + t;
        const int r = idx >> 4;
        const int c = (idx & 15) * 4;
        const int rn = (r < nvalid) ? r : (nvalid - 1);
        *reinterpret_cast<float4*>(xs + r * 68 + c) =
            *reinterpret_cast<const float4*>(xc + (size_t)(base + rn) * CH + c);
    }
    __syncthreads();

    // layer 1: y1 = relu(x@W1 + b1)
    float acc[4][4];
    #pragma unroll
    for (int i = 0; i < 4; ++i)
        #pragma unroll
        for (int j = 0; j < 4; ++j) acc[i][j] = 0.f;
    for (int k = 0; k < 64; k += 4) {
        float av[4][4];
        #pragma unroll
        for (int i = 0; i < 4; ++i) {
            const float4 v = *reinterpret_cast<const float4*>(xs + (r0 + i) * 68 + k);
            av[i][0] = v.x; av[i][1] = v.y; av[i][2] = v.z; av[i][3] = v.w;
        }
        #pragma unroll
        for (int kk = 0; kk < 4; ++kk) {
            const float4 w = *reinterpret_cast<const float4*>(W1 + (k + kk) * CH + j2);
            const float wv[4] = {w.x, w.y, w.z, w.w};
            #pragma unroll
            for (int i = 0; i < 4; ++i)
                #pragma unroll
                for (int j = 0; j < 4; ++j)
                    acc[i][j] = fmaf(av[i][kk], wv[j], acc[i][j]);
        }
    }
    const float4 bb = *reinterpret_cast<const float4*>(b1 + j2);
    __syncthreads();
    #pragma unroll
    for (int i = 0; i < 4; ++i) {
        float4 v;
        v.x = fmaxf(acc[i][0] + bb.x, 0.f);
        v.y = fmaxf(acc[i][1] + bb.y, 0.f);
        v.z = fmaxf(acc[i][2] + bb.z, 0.f);
        v.w = fmaxf(acc[i][3] + bb.w, 0.f);
        *reinterpret_cast<float4*>(xs + (r0 + i) * 68 + j2) = v;   // y1 -> xs
    }
    __syncthreads();

    // layer 2: y2 = relu(y1@W2 + b2)
    float acc2[4][4];
    #pragma unroll
    for (int i = 0; i < 4; ++i)
        #pragma unroll
        for (int j = 0; j < 4; ++j) acc2[i][j] = 0.f;
    for (int k = 0; k < 64; k += 4) {
        float av[4][4];
        #pragma unroll
        for (int i = 0; i < 4; ++i) {
            const float4 v = *reinterpret_cast<const float4*>(xs + (r0 + i) * 68 + k);
            av[i][0] = v.x; av[i][1] = v.y; av[i][2] = v.z; av[i][3] = v.w;
        }
        #pragma unroll
        for (int kk = 0; kk < 4; ++kk) {
            const float4 w = *reinterpret_cast<const float4*>(W2 + (k + kk) * CH + j2);
            const float wv[4] = {w.x, w.y, w.z, w.w};
            #pragma unroll
            for (int i = 0; i < 4; ++i)
                #pragma unroll
                for (int j = 0; j < 4; ++j)
                    acc2[i][j] = fmaf(av[i][kk], wv[j], acc2[i][j]);
        }
    }
    const float4 bb2 = *reinterpret_cast<const float4*>(b2 + j2);
    __syncthreads();
    #pragma unroll
    for (int i = 0; i < 4; ++i) {
        float4 v;
        v.x = fmaxf(acc2[i][0] + bb2.x, 0.f);
        v.y = fmaxf(acc2[i][1] + bb2.y, 0.f);
        v.z = fmaxf(acc2[i][2] + bb2.z, 0.f);
        v.w = fmaxf(acc2[i][3] + bb2.w, 0.f);
        *reinterpret_cast<float4*>(xs + (r0 + i) * 68 + j2) = v;   // y2 -> xs
    }
    __syncthreads();

    // layer 3: out[r] = y2[r] @ W3 + b3
    const int rr = t >> 2, qq = t & 3;
    float p0 = 0.f, p1 = 0.f;
    #pragma unroll
    for (int c = 0; c < 16; ++c) {
        const float y = xs[rr * 68 + qq * 16 + c];
        p0 = fmaf(y, W3[(qq * 16 + c) * 2 + 0], p0);
        p1 = fmaf(y, W3[(qq * 16 + c) * 2 + 1], p1);
    }
    #pragma unroll
    for (int o = 1; o <= 2; o <<= 1) {
        p0 += __shfl_xor(p0, o);
        p1 += __shfl_xor(p1, o);
    }
    if (qq == 0 && rr < nvalid) {
        float2 st; st.x = p0 + b3[0]; st.y = p1 + b3[1];
        *reinterpret_cast<float2*>(out + (size_t)(base + rr) * 2) = st;
    }
}

extern "C" void kernel_launch(void* const* d_in, const int* in_sizes, int n_in,
                              void* d_out, int out_size, void* d_ws, size_t ws_size,
                              hipStream_t stream)
{
    const float* x     = (const float*)d_in[0];
    const int*   ei    = (const int*)d_in[1];
    const float* c1W1  = (const float*)d_in[2];
    const float* c1b1  = (const float*)d_in[3];
    const float* c1lnw = (const float*)d_in[4];
    const float* c1lnb = (const float*)d_in[5];
    const float* c1W2  = (const float*)d_in[6];
    const float* c1b2  = (const float*)d_in[7];
    const float* n1w   = (const float*)d_in[8];
    const float* n1b   = (const float*)d_in[9];
    const float* cW1   = (const float*)d_in[10];
    const float* cb1   = (const float*)d_in[11];
    const float* clnw  = (const float*)d_in[12];
    const float* clnb  = (const float*)d_in[13];
    const float* cW2   = (const float*)d_in[14];
    const float* cb2   = (const float*)d_in[15];
    const float* nw    = (const float*)d_in[16];
    const float* nb    = (const float*)d_in[17];
    const float* lW1   = (const float*)d_in[18];
    const float* lb1   = (const float*)d_in[19];
    const float* lW2   = (const float*)d_in[20];
    const float* lb2   = (const float*)d_in[21];
    const float* lW3   = (const float*)d_in[22];
    const float* lb3   = (const float*)d_in[23];
    float* out = (float*)d_out;

    float* bufA = (float*)d_ws;
    float* bufB = bufA + NC;
    float* hbuf = bufB + NC;
    int* cursor = (int*)(hbuf + NC);
    int* off    = cursor + NN;
    int* esrc   = off + NN + 2;
    int* part   = esrc + NE;
    double* dsum = (double*)(part + 256);

    hipMemsetAsync(cursor, 0, NN * sizeof(int), stream);
    hipMemsetAsync(dsum, 0, 10 * sizeof(double), stream);
    hist_kernel<<<3125, 256, 0, stream>>>(ei, cursor);
    scan1_kernel<<<SB, 256, 0, stream>>>(cursor, part);
    scan2_kernel<<<1, 128, 0, stream>>>(part, off);
    scan3_kernel<<<SB, 256, 0, stream>>>(part, cursor, off);
    scatter_kernel<<<3125, 256, 0, stream>>>(ei, cursor, esrc);

    const int AGG_BLOCKS = 25000;   // wave per node

    // layer 1 (plain)
    agg_kernel<0><<<AGG_BLOCKS, 256, 0, stream>>>(x, off, esrc, nullptr, nullptr, nullptr, hbuf);
    conv_mlp_kernel<0><<<NT, 256, 0, stream>>>(hbuf, nullptr, c1W1, c1b1, c1lnw, c1lnb,
                                               c1W2, c1b2, bufA, dsum + 0);
    ln_apply_kernel<<<2048, 256, 0, stream>>>(bufA, n1w, n1b, dsum + 0, bufB, dsum + 2);

    // layers 2..4 (res+), ping-pong xc between bufB/bufA
    agg_kernel<1><<<AGG_BLOCKS, 256, 0, stream>>>(bufB, off, esrc, dsum + 2, nw + 0, nb + 0, hbuf);
    conv_mlp_kernel<1><<<NT, 256, 0, stream>>>(hbuf, bufB, cW1 + 0 * 8192, cb1 + 0 * 128,
                                               clnw + 0 * 128, clnb + 0 * 128,
                                               cW2 + 0 * 8192, cb2 + 0 * 64, bufA, dsum + 4);

    agg_kernel<1><<<AGG_BLOCKS, 256, 0, stream>>>(bufA, off, esrc, dsum + 4, nw + 64, nb + 64, hbuf);
    conv_mlp_kernel<1><<<NT, 256, 0, stream>>>(hbuf, bufA, cW1 + 1 * 8192, cb1 + 1 * 128,
                                               clnw + 1 * 128, clnb + 1 * 128,
                                               cW2 + 1 * 8192, cb2 + 1 * 64, bufB, dsum + 6);

    agg_kernel<1><<<AGG_BLOCKS, 256, 0, stream>>>(bufB, off, esrc, dsum + 6, nw + 128, nb + 128, hbuf);
    conv_mlp_kernel<1><<<NT, 256, 0, stream>>>(hbuf, bufB, cW1 + 2 * 8192, cb1 + 2 * 128,
                                               clnw + 2 * 128, clnb + 2 * 128,
                                               cW2 + 2 * 8192, cb2 + 2 * 64, bufA, dsum + 8);

    // dense head
    head_kernel<<<NT, 256, 0, stream>>>(bufA, lW1, lb1, lW2, lb2, lW3, lb3, out);
}

// Round 8
// 701.450 us; speedup vs baseline: 1.0629x; 1.0629x over previous
//
#include <hip/hip_runtime.h>

// DeeperGCN round 8.
// r6: W1 in LDS, j0=tx*8 -> 4-way bank conflict (3.6M cyc), conv=68us.
// r7: W1 from global -> conflict 0 but VMEM-pipe bound (VALU 46->34%), conv=89us.
// r8: W1 in LDS [64][128] + split-j0 {tx*4, 64+tx*4} reads -> 256B contiguous
// per 16-lane group = 2-way (free) + ty broadcast (free). Phase A on LDS pipe,
// phase B (W2) on VMEM pipe. LDS 49KB (X 64x68 + W1 64x128, H' 64x132 reuses).
// agg: unguarded full-batch fast path.

#define NN 100000
#define NE 800000
#define CH 64
#define NC (NN * CH)
#define H1 128
#define NT 1563            // ceil(NN / 64) node tiles
#define SB 98              // scan blocks
#define EPS_MSG 1e-7f
#define EPS_LN 1e-5f

// ---------------- counting sort: histogram ----------------
__global__ __launch_bounds__(256) void hist_kernel(const int* __restrict__ ei,
                                                   int* __restrict__ cursor) {
    int e = blockIdx.x * 256 + threadIdx.x;
    if (e < NE) atomicAdd(&cursor[ei[NE + e]], 1);
}

// ---------------- hierarchical scan ----------------
__global__ __launch_bounds__(256) void scan1_kernel(const int* __restrict__ cursor,
                                                    int* __restrict__ part) {
    __shared__ int sp[4];
    const int t = threadIdx.x;
    const int i0 = blockIdx.x * 1024 + t * 4;
    int s = 0;
    #pragma unroll
    for (int j = 0; j < 4; ++j) { int i = i0 + j; if (i < NN) s += cursor[i]; }
    #pragma unroll
    for (int o = 32; o; o >>= 1) s += __shfl_xor(s, o);
    if ((t & 63) == 0) sp[t >> 6] = s;
    __syncthreads();
    if (t == 0) part[blockIdx.x] = sp[0] + sp[1] + sp[2] + sp[3];
}

__global__ __launch_bounds__(128) void scan2_kernel(int* __restrict__ part,
                                                    int* __restrict__ off) {
    __shared__ int sc[128];
    const int t = threadIdx.x;
    int v = (t < SB) ? part[t] : 0;
    sc[t] = v;
    __syncthreads();
    for (int o = 1; o < 128; o <<= 1) {
        int u = (t >= o) ? sc[t - o] : 0;
        __syncthreads();
        sc[t] += u;
        __syncthreads();
    }
    if (t < SB) part[t] = sc[t] - v;
    if (t == 0) off[NN] = NE;
}

__global__ __launch_bounds__(256) void scan3_kernel(const int* __restrict__ part,
                                                    int* __restrict__ cursor,
                                                    int* __restrict__ off) {
    __shared__ int sc[256];
    const int t = threadIdx.x;
    const int i0 = blockIdx.x * 1024 + t * 4;
    int deg[4];
    int s = 0;
    #pragma unroll
    for (int j = 0; j < 4; ++j) { int i = i0 + j; deg[j] = (i < NN) ? cursor[i] : 0; s += deg[j]; }
    sc[t] = s;
    __syncthreads();
    for (int o = 1; o < 256; o <<= 1) {
        int u = (t >= o) ? sc[t - o] : 0;
        __syncthreads();
        sc[t] += u;
        __syncthreads();
    }
    int run = part[blockIdx.x] + sc[t] - s;
    #pragma unroll
    for (int j = 0; j < 4; ++j) {
        int i = i0 + j;
        if (i < NN) { off[i] = run; cursor[i] = run; run += deg[j]; }
    }
}

// ---------------- scatter src ids grouped by dst ----------------
__global__ __launch_bounds__(256) void scatter_kernel(const int* __restrict__ ei,
                                                      int* __restrict__ cursor,
                                                      int* __restrict__ esrc) {
    int e = blockIdx.x * 256 + threadIdx.x;
    if (e >= NE) return;
    int dst = ei[NE + e];
    int pos = atomicAdd(&cursor[dst], 1);
    esrc[pos] = ei[e];
}

// ---------------- aggregation: wave per node, channel per lane ----------------
template <int MODE>
__global__ __launch_bounds__(256) void agg_kernel(
    const float* __restrict__ xin, const int* __restrict__ off,
    const int* __restrict__ esrc, const double* __restrict__ ds_in,
    const float* __restrict__ gw, const float* __restrict__ gb,
    float* __restrict__ hbuf)
{
    const int lane = threadIdx.x & 63;
    const int n = __builtin_amdgcn_readfirstlane((blockIdx.x * 256 + threadIdx.x) >> 6);
    if (n >= NN) return;
    float A = 1.f, B = 0.f;
    if (MODE) {
        double S = ds_in[0], Q = ds_in[1];
        double mud = S / (double)NC;
        float var = (float)(Q / (double)NC - mud * mud);
        float scale = 1.f / (sqrtf(fmaxf(var, 0.f)) + EPS_LN);
        A = scale * gw[lane];
        B = fmaf(-(float)mud, A, gb[lane]);
    }
    const size_t base = (size_t)n * CH + lane;
    const float xb = xin[base];
    const int p0 = off[n], p1 = off[n + 1];
    float den = 0.f, num = 0.f;
    int q = p0;
    // full-batch fast path: no per-element guards
    for (; q + 8 <= p1; q += 8) {
        float v[8];
        #pragma unroll
        for (int i = 0; i < 8; ++i)
            v[i] = xin[(size_t)esrc[q + i] * CH + lane];
        #pragma unroll
        for (int i = 0; i < 8; ++i) {
            float mm = MODE ? fmaxf(fmaf(v[i], A, B), 0.f) + EPS_MSG
                            : fmaxf(v[i], 0.f) + EPS_MSG;
            float e = __expf(mm);
            den += e;
            num = fmaf(mm, e, num);
        }
    }
    // tail
    for (; q < p1; ++q) {
        float v = xin[(size_t)esrc[q] * CH + lane];
        float mm = MODE ? fmaxf(fmaf(v, A, B), 0.f) + EPS_MSG
                        : fmaxf(v, 0.f) + EPS_MSG;
        float e = __expf(mm);
        den += e;
        num = fmaf(mm, e, num);
    }
    float agg = den > 0.f ? num / den : 0.f;
    float xl = MODE ? fmaxf(fmaf(xb, A, B), 0.f) : xb;
    hbuf[base] = agg + xl;
}

// ---------------- fused conv MLP: block-tiled double GEMM ----------------
// Phase A: H = X@W1+b1, X + W1 in LDS (split-j0 conflict-free reads);
// row-LN+relu via shfl; H' -> LDS (reused region); Phase B: O = H'@W2+b2 (W2 global/L1).
template <int MODE>
__global__ __launch_bounds__(256) void conv_mlp_kernel(
    const float* __restrict__ hbuf, const float* __restrict__ xres,
    const float* __restrict__ W1, const float* __restrict__ b1,
    const float* __restrict__ lnw, const float* __restrict__ lnb,
    const float* __restrict__ W2, const float* __restrict__ b2,
    float* __restrict__ out, double* __restrict__ ds_out)
{
    __shared__ float smem[12544];       // 50.2 KB: [X 64x68 | W1 64x128] -> H' 64x132
    __shared__ float sstat[8];
    float* xs  = smem;                  // [64][68]
    float* w1s = smem + 4352;           // [64][128]
    float* hs  = smem;                  // [64][132] (phase B)
    const int t = threadIdx.x;
    const int base = blockIdx.x * 64;
    const int nvalid = (NN - base < 64) ? (NN - base) : 64;

    // stage X tile (row-clamped) and W1
    #pragma unroll
    for (int j = 0; j < 4; ++j) {
        const int idx = j * 256 + t;            // 1024 float4s, 16 per row
        const int r = idx >> 4;
        const int c = (idx & 15) * 4;
        const int rn = (r < nvalid) ? r : (nvalid - 1);
        *reinterpret_cast<float4*>(xs + r * 68 + c) =
            *reinterpret_cast<const float4*>(hbuf + (size_t)(base + rn) * CH + c);
    }
    #pragma unroll
    for (int j = 0; j < 8; ++j) {
        const int idx = j * 256 + t;            // 2048 float4s, 32 per row
        const int r = idx >> 5;
        const int c = (idx & 31) * 4;
        *reinterpret_cast<float4*>(w1s + r * H1 + c) =
            *reinterpret_cast<const float4*>(W1 + r * H1 + c);
    }
    __syncthreads();

    const int tx = t & 15, ty = t >> 4;
    const int r0 = ty * 4;              // 4 node-rows
    const int j0 = tx * 4;              // cols j0..j0+3 and 64+j0..64+j0+3

    // phase A: acc[i][0..3] = cols j0, acc[i][4..7] = cols 64+j0
    float acc[4][8];
    #pragma unroll
    for (int i = 0; i < 4; ++i)
        #pragma unroll
        for (int j = 0; j < 8; ++j) acc[i][j] = 0.f;
    for (int k = 0; k < 64; k += 4) {
        float av[4][4];
        #pragma unroll
        for (int i = 0; i < 4; ++i) {
            const float4 v = *reinterpret_cast<const float4*>(xs + (r0 + i) * 68 + k);
            av[i][0] = v.x; av[i][1] = v.y; av[i][2] = v.z; av[i][3] = v.w;
        }
        #pragma unroll
        for (int kk = 0; kk < 4; ++kk) {
            const float4 w0 = *reinterpret_cast<const float4*>(w1s + (k + kk) * H1 + j0);
            const float4 w1v = *reinterpret_cast<const float4*>(w1s + (k + kk) * H1 + 64 + j0);
            const float bv[8] = {w0.x, w0.y, w0.z, w0.w, w1v.x, w1v.y, w1v.z, w1v.w};
            #pragma unroll
            for (int i = 0; i < 4; ++i)
                #pragma unroll
                for (int j = 0; j < 8; ++j)
                    acc[i][j] = fmaf(av[i][kk], bv[j], acc[i][j]);
        }
    }

    // + b1, per-row LN stats (row spread over 16 tx lanes)
    {
        const float4 bb0 = *reinterpret_cast<const float4*>(b1 + j0);
        const float4 bb1 = *reinterpret_cast<const float4*>(b1 + 64 + j0);
        const float bj[8] = {bb0.x, bb0.y, bb0.z, bb0.w, bb1.x, bb1.y, bb1.z, bb1.w};
        #pragma unroll
        for (int i = 0; i < 4; ++i)
            #pragma unroll
            for (int j = 0; j < 8; ++j) acc[i][j] += bj[j];
    }
    float rs[4], rq[4];
    #pragma unroll
    for (int i = 0; i < 4; ++i) {
        float s = 0.f, q = 0.f;
        #pragma unroll
        for (int j = 0; j < 8; ++j) { s += acc[i][j]; q = fmaf(acc[i][j], acc[i][j], q); }
        rs[i] = s; rq[i] = q;
    }
    #pragma unroll
    for (int o = 1; o <= 8; o <<= 1) {
        #pragma unroll
        for (int i = 0; i < 4; ++i) {
            rs[i] += __shfl_xor(rs[i], o);
            rq[i] += __shfl_xor(rq[i], o);
        }
    }
    // normalize + affine + relu
    {
        const float4 g0 = *reinterpret_cast<const float4*>(lnw + j0);
        const float4 g1 = *reinterpret_cast<const float4*>(lnw + 64 + j0);
        const float4 c0 = *reinterpret_cast<const float4*>(lnb + j0);
        const float4 c1 = *reinterpret_cast<const float4*>(lnb + 64 + j0);
        const float gj[8] = {g0.x, g0.y, g0.z, g0.w, g1.x, g1.y, g1.z, g1.w};
        const float cj[8] = {c0.x, c0.y, c0.z, c0.w, c1.x, c1.y, c1.z, c1.w};
        #pragma unroll
        for (int i = 0; i < 4; ++i) {
            const float mu = rs[i] * (1.f / 128.f);
            const float var = rq[i] * (1.f / 128.f) - mu * mu;
            const float rstd = 1.f / sqrtf(var + EPS_LN);
            #pragma unroll
            for (int j = 0; j < 8; ++j)
                acc[i][j] = fmaxf(fmaf((acc[i][j] - mu) * rstd, gj[j], cj[j]), 0.f);
        }
    }
    __syncthreads();                    // everyone done reading xs/w1s
    #pragma unroll
    for (int i = 0; i < 4; ++i) {
        float4 v0, v1;
        v0.x = acc[i][0]; v0.y = acc[i][1]; v0.z = acc[i][2]; v0.w = acc[i][3];
        v1.x = acc[i][4]; v1.y = acc[i][5]; v1.z = acc[i][6]; v1.w = acc[i][7];
        *reinterpret_cast<float4*>(hs + (r0 + i) * 132 + j0) = v0;
        *reinterpret_cast<float4*>(hs + (r0 + i) * 132 + 64 + j0) = v1;
    }
    __syncthreads();

    // phase B: O = H' @ W2 + b2 ; W2 rows from global (L1-resident)
    const int j2 = tx * 4;
    float acc2[4][4];
    #pragma unroll
    for (int i = 0; i < 4; ++i)
        #pragma unroll
        for (int j = 0; j < 4; ++j) acc2[i][j] = 0.f;
    for (int k = 0; k < 128; k += 4) {
        float av[4][4];
        #pragma unroll
        for (int i = 0; i < 4; ++i) {
            const float4 v = *reinterpret_cast<const float4*>(hs + (r0 + i) * 132 + k);
            av[i][0] = v.x; av[i][1] = v.y; av[i][2] = v.z; av[i][3] = v.w;
        }
        #pragma unroll
        for (int kk = 0; kk < 4; ++kk) {
            const float4 w = *reinterpret_cast<const float4*>(W2 + (k + kk) * CH + j2);
            const float wv[4] = {w.x, w.y, w.z, w.w};
            #pragma unroll
            for (int i = 0; i < 4; ++i)
                #pragma unroll
                for (int j = 0; j < 4; ++j)
                    acc2[i][j] = fmaf(av[i][kk], wv[j], acc2[i][j]);
        }
    }

    // epilogue: +b2, +residual, store, stats
    const float4 b2v = *reinterpret_cast<const float4*>(b2 + j2);
    float as = 0.f, aq = 0.f;
    #pragma unroll
    for (int i = 0; i < 4; ++i) {
        const int r = r0 + i;
        if (r < nvalid) {
            float v0 = acc2[i][0] + b2v.x;
            float v1 = acc2[i][1] + b2v.y;
            float v2 = acc2[i][2] + b2v.z;
            float v3 = acc2[i][3] + b2v.w;
            const size_t gi = (size_t)(base + r) * CH + j2;
            if (MODE) {
                const float4 xr = *reinterpret_cast<const float4*>(xres + gi);
                v0 += xr.x; v1 += xr.y; v2 += xr.z; v3 += xr.w;
            }
            float4 st; st.x = v0; st.y = v1; st.z = v2; st.w = v3;
            *reinterpret_cast<float4*>(out + gi) = st;
            as += (v0 + v1) + (v2 + v3);
            aq += fmaf(v0, v0, v1 * v1) + fmaf(v2, v2, v3 * v3);
        }
    }
    #pragma unroll
    for (int o = 32; o; o >>= 1) { as += __shfl_xor(as, o); aq += __shfl_xor(aq, o); }
    const int lane = t & 63, wv2 = t >> 6;
    if (lane == 0) { sstat[wv2] = as; sstat[4 + wv2] = aq; }
    __syncthreads();
    if (t == 0) {
        unsafeAtomicAdd(ds_out + 0, (double)(sstat[0] + sstat[1] + sstat[2] + sstat[3]));
        unsafeAtomicAdd(ds_out + 1, (double)(sstat[4] + sstat[5] + sstat[6] + sstat[7]));
    }
}

// ---------------- layer-1 graph-LN apply (+relu) with output stats ----------------
__global__ __launch_bounds__(256) void ln_apply_kernel(
    const float* __restrict__ in, const float* __restrict__ w,
    const float* __restrict__ b, const double* __restrict__ ds_in,
    float* __restrict__ out, double* __restrict__ ds_out)
{
    __shared__ float ps[4], pq[4];
    double S = ds_in[0], Q = ds_in[1];
    double mud = S / (double)NC;
    float mu = (float)mud;
    float var = (float)(Q / (double)NC - mud * mud);
    float scale = 1.f / (sqrtf(fmaxf(var, 0.f)) + EPS_LN);
    float s = 0.f, q = 0.f;
    int idx = blockIdx.x * 256 + threadIdx.x;
    int stride = gridDim.x * 256;
    for (int i = idx; i < NC / 4; i += stride) {
        int c = (i & 15) << 2;
        float4 v = reinterpret_cast<const float4*>(in)[i];
        float4 wv = *reinterpret_cast<const float4*>(w + c);
        float4 bv = *reinterpret_cast<const float4*>(b + c);
        float4 o;
        o.x = fmaxf(fmaf((v.x - mu) * scale, wv.x, bv.x), 0.f);
        o.y = fmaxf(fmaf((v.y - mu) * scale, wv.y, bv.y), 0.f);
        o.z = fmaxf(fmaf((v.z - mu) * scale, wv.z, bv.z), 0.f);
        o.w = fmaxf(fmaf((v.w - mu) * scale, wv.w, bv.w), 0.f);
        reinterpret_cast<float4*>(out)[i] = o;
        s += (o.x + o.y) + (o.z + o.w);
        q += fmaf(o.x, o.x, o.y * o.y) + fmaf(o.z, o.z, o.w * o.w);
    }
    int lane = threadIdx.x & 63, wv2 = threadIdx.x >> 6;
    #pragma unroll
    for (int o = 32; o; o >>= 1) { s += __shfl_xor(s, o); q += __shfl_xor(q, o); }
    if (lane == 0) { ps[wv2] = s; pq[wv2] = q; }
    __syncthreads();
    if (threadIdx.x == 0) {
        unsafeAtomicAdd(ds_out + 0, (double)((ps[0] + ps[1]) + (ps[2] + ps[3])));
        unsafeAtomicAdd(ds_out + 1, (double)((pq[0] + pq[1]) + (pq[2] + pq[3])));
    }
}

// ---------------- head: block-tiled GEMMs, X/Y tile in LDS, weights global ----------------
__global__ __launch_bounds__(256) void head_kernel(
    const float* __restrict__ xc,
    const float* __restrict__ W1, const float* __restrict__ b1,
    const float* __restrict__ W2, const float* __restrict__ b2,
    const float* __restrict__ W3, const float* __restrict__ b3,
    float* __restrict__ out)
{
    __shared__ float xs[64 * 68];       // 17.4 KB
    const int t = threadIdx.x;
    const int base = blockIdx.x * 64;
    const int nvalid = (NN - base < 64) ? (NN - base) : 64;
    const int tx = t & 15, ty = t >> 4;
    const int r0 = ty * 4, j2 = tx * 4;

    #pragma unroll
    for (int j = 0; j < 4; ++j) {
        const int idx = j * 256 + t;
        const int r = idx >> 4;
        const int c = (idx & 15) * 4;
        const int rn = (r < nvalid) ? r : (nvalid - 1);
        *reinterpret_cast<float4*>(xs + r * 68 + c) =
            *reinterpret_cast<const float4*>(xc + (size_t)(base + rn) * CH + c);
    }
    __syncthreads();

    // layer 1: y1 = relu(x@W1 + b1)
    float acc[4][4];
    #pragma unroll
    for (int i = 0; i < 4; ++i)
        #pragma unroll
        for (int j = 0; j < 4; ++j) acc[i][j] = 0.f;
    for (int k = 0; k < 64; k += 4) {
        float av[4][4];
        #pragma unroll
        for (int i = 0; i < 4; ++i) {
            const float4 v = *reinterpret_cast<const float4*>(xs + (r0 + i) * 68 + k);
            av[i][0] = v.x; av[i][1] = v.y; av[i][2] = v.z; av[i][3] = v.w;
        }
        #pragma unroll
        for (int kk = 0; kk < 4; ++kk) {
            const float4 w = *reinterpret_cast<const float4*>(W1 + (k + kk) * CH + j2);
            const float wv[4] = {w.x, w.y, w.z, w.w};
            #pragma unroll
            for (int i = 0; i < 4; ++i)
                #pragma unroll
                for (int j = 0; j < 4; ++j)
                    acc[i][j] = fmaf(av[i][kk], wv[j], acc[i][j]);
        }
    }
    const float4 bb = *reinterpret_cast<const float4*>(b1 + j2);
    __syncthreads();
    #pragma unroll
    for (int i = 0; i < 4; ++i) {
        float4 v;
        v.x = fmaxf(acc[i][0] + bb.x, 0.f);
        v.y = fmaxf(acc[i][1] + bb.y, 0.f);
        v.z = fmaxf(acc[i][2] + bb.z, 0.f);
        v.w = fmaxf(acc[i][3] + bb.w, 0.f);
        *reinterpret_cast<float4*>(xs + (r0 + i) * 68 + j2) = v;   // y1 -> xs
    }
    __syncthreads();

    // layer 2: y2 = relu(y1@W2 + b2)
    float acc2[4][4];
    #pragma unroll
    for (int i = 0; i < 4; ++i)
        #pragma unroll
        for (int j = 0; j < 4; ++j) acc2[i][j] = 0.f;
    for (int k = 0; k < 64; k += 4) {
        float av[4][4];
        #pragma unroll
        for (int i = 0; i < 4; ++i) {
            const float4 v = *reinterpret_cast<const float4*>(xs + (r0 + i) * 68 + k);
            av[i][0] = v.x; av[i][1] = v.y; av[i][2] = v.z; av[i][3] = v.w;
        }
        #pragma unroll
        for (int kk = 0; kk < 4; ++kk) {
            const float4 w = *reinterpret_cast<const float4*>(W2 + (k + kk) * CH + j2);
            const float wv[4] = {w.x, w.y, w.z, w.w};
            #pragma unroll
            for (int i = 0; i < 4; ++i)
                #pragma unroll
                for (int j = 0; j < 4; ++j)
                    acc2[i][j] = fmaf(av[i][kk], wv[j], acc2[i][j]);
        }
    }
    const float4 bb2 = *reinterpret_cast<const float4*>(b2 + j2);
    __syncthreads();
    #pragma unroll
    for (int i = 0; i < 4; ++i) {
        float4 v;
        v.x = fmaxf(acc2[i][0] + bb2.x, 0.f);
        v.y = fmaxf(acc2[i][1] + bb2.y, 0.f);
        v.z = fmaxf(acc2[i][2] + bb2.z, 0.f);
        v.w = fmaxf(acc2[i][3] + bb2.w, 0.f);
        *reinterpret_cast<float4*>(xs + (r0 + i) * 68 + j2) = v;   // y2 -> xs
    }
    __syncthreads();

    // layer 3: out[r] = y2[r] @ W3 + b3
    const int rr = t >> 2, qq = t & 3;
    float p0 = 0.f, p1 = 0.f;
    #pragma unroll
    for (int c = 0; c < 16; ++c) {
        const float y = xs[rr * 68 + qq * 16 + c];
        p0 = fmaf(y, W3[(qq * 16 + c) * 2 + 0], p0);
        p1 = fmaf(y, W3[(qq * 16 + c) * 2 + 1], p1);
    }
    #pragma unroll
    for (int o = 1; o <= 2; o <<= 1) {
        p0 += __shfl_xor(p0, o);
        p1 += __shfl_xor(p1, o);
    }
    if (qq == 0 && rr < nvalid) {
        float2 st; st.x = p0 + b3[0]; st.y = p1 + b3[1];
        *reinterpret_cast<float2*>(out + (size_t)(base + rr) * 2) = st;
    }
}

extern "C" void kernel_launch(void* const* d_in, const int* in_sizes, int n_in,
                              void* d_out, int out_size, void* d_ws, size_t ws_size,
                              hipStream_t stream)
{
    const float* x     = (const float*)d_in[0];
    const int*   ei    = (const int*)d_in[1];
    const float* c1W1  = (const float*)d_in[2];
    const float* c1b1  = (const float*)d_in[3];
    const float* c1lnw = (const float*)d_in[4];
    const float* c1lnb = (const float*)d_in[5];
    const float* c1W2  = (const float*)d_in[6];
    const float* c1b2  = (const float*)d_in[7];
    const float* n1w   = (const float*)d_in[8];
    const float* n1b   = (const float*)d_in[9];
    const float* cW1   = (const float*)d_in[10];
    const float* cb1   = (const float*)d_in[11];
    const float* clnw  = (const float*)d_in[12];
    const float* clnb  = (const float*)d_in[13];
    const float* cW2   = (const float*)d_in[14];
    const float* cb2   = (const float*)d_in[15];
    const float* nw    = (const float*)d_in[16];
    const float* nb    = (const float*)d_in[17];
    const float* lW1   = (const float*)d_in[18];
    const float* lb1   = (const float*)d_in[19];
    const float* lW2   = (const float*)d_in[20];
    const float* lb2   = (const float*)d_in[21];
    const float* lW3   = (const float*)d_in[22];
    const float* lb3   = (const float*)d_in[23];
    float* out = (float*)d_out;

    float* bufA = (float*)d_ws;
    float* bufB = bufA + NC;
    float* hbuf = bufB + NC;
    int* cursor = (int*)(hbuf + NC);
    int* off    = cursor + NN;
    int* esrc   = off + NN + 2;
    int* part   = esrc + NE;
    double* dsum = (double*)(part + 256);

    hipMemsetAsync(cursor, 0, NN * sizeof(int), stream);
    hipMemsetAsync(dsum, 0, 10 * sizeof(double), stream);
    hist_kernel<<<3125, 256, 0, stream>>>(ei, cursor);
    scan1_kernel<<<SB, 256, 0, stream>>>(cursor, part);
    scan2_kernel<<<1, 128, 0, stream>>>(part, off);
    scan3_kernel<<<SB, 256, 0, stream>>>(part, cursor, off);
    scatter_kernel<<<3125, 256, 0, stream>>>(ei, cursor, esrc);

    const int AGG_BLOCKS = 25000;   // wave per node

    // layer 1 (plain)
    agg_kernel<0><<<AGG_BLOCKS, 256, 0, stream>>>(x, off, esrc, nullptr, nullptr, nullptr, hbuf);
    conv_mlp_kernel<0><<<NT, 256, 0, stream>>>(hbuf, nullptr, c1W1, c1b1, c1lnw, c1lnb,
                                               c1W2, c1b2, bufA, dsum + 0);
    ln_apply_kernel<<<2048, 256, 0, stream>>>(bufA, n1w, n1b, dsum + 0, bufB, dsum + 2);

    // layers 2..4 (res+), ping-pong xc between bufB/bufA
    agg_kernel<1><<<AGG_BLOCKS, 256, 0, stream>>>(bufB, off, esrc, dsum + 2, nw + 0, nb + 0, hbuf);
    conv_mlp_kernel<1><<<NT, 256, 0, stream>>>(hbuf, bufB, cW1 + 0 * 8192, cb1 + 0 * 128,
                                               clnw + 0 * 128, clnb + 0 * 128,
                                               cW2 + 0 * 8192, cb2 + 0 * 64, bufA, dsum + 4);

    agg_kernel<1><<<AGG_BLOCKS, 256, 0, stream>>>(bufA, off, esrc, dsum + 4, nw + 64, nb + 64, hbuf);
    conv_mlp_kernel<1><<<NT, 256, 0, stream>>>(hbuf, bufA, cW1 + 1 * 8192, cb1 + 1 * 128,
                                               clnw + 1 * 128, clnb + 1 * 128,
                                               cW2 + 1 * 8192, cb2 + 1 * 64, bufB, dsum + 6);

    agg_kernel<1><<<AGG_BLOCKS, 256, 0, stream>>>(bufB, off, esrc, dsum + 6, nw + 128, nb + 128, hbuf);
    conv_mlp_kernel<1><<<NT, 256, 0, stream>>>(hbuf, bufB, cW1 + 2 * 8192, cb1 + 2 * 128,
                                               clnw + 2 * 128, clnb + 2 * 128,
                                               cW2 + 2 * 8192, cb2 + 2 * 64, bufA, dsum + 8);

    // dense head
    head_kernel<<<NT, 256, 0, stream>>>(bufA, lW1, lb1, lW2, lb2, lW3, lb3, out);
}